// Round 1
// baseline (193.747 us; speedup 1.0000x reference)
//
#include <hip/hip_runtime.h>
#include <hip/hip_bf16.h>

// SubjectSpecificProjection: per-subject 2-layer MLP (256->512->512) + L2 normalize.
// Strategy: bucket samples by subject, pre-convert/transpose weights to bf16 in ws,
// fused grouped-GEMM with mfma_f32_16x16x32_bf16, fp32 accum, fused normalize.

#define BATCH 16384
#define EEG 256
#define CLIP 512
#define NSUB 13
#define ROWS 64

typedef unsigned short u16;
typedef __attribute__((ext_vector_type(8))) short short8;
typedef __attribute__((ext_vector_type(4))) float f32x4;

__device__ __forceinline__ u16 f2bf(float f) {
    union { float f; unsigned int u; } v; v.f = f;
    unsigned int u = v.u;
    unsigned int r = (u + 0x7FFFu + ((u >> 16) & 1u)) >> 16;   // RNE
    return (u16)r;
}

// ---- weight convert + transpose: W[s][k][n] fp32 -> Wt[s][n][k] bf16 ----
__global__ __launch_bounds__(256) void convert_transpose(
    const float* __restrict__ W1, const float* __restrict__ W2,
    u16* __restrict__ w1t, u16* __restrict__ w2t) {
    __shared__ u16 T[64][72];   // 72: 144B row stride, 16B aligned, bank-spread
    int b = blockIdx.x;
    const float* src; u16* dst; int K, N;
    int s, k0, n0;
    if (b < 416) {               // W1: 13 subjects x (256/64)x(512/64)=32 tiles
        s = b >> 5; int t = b & 31;
        k0 = (t >> 3) << 6; n0 = (t & 7) << 6;
        K = EEG; N = CLIP;
        src = W1 + (size_t)s * EEG * CLIP;
        dst = w1t + (size_t)s * CLIP * EEG;
    } else {                     // W2: 13 x 64 tiles
        b -= 416; s = b >> 6; int t = b & 63;
        k0 = (t >> 3) << 6; n0 = (t & 7) << 6;
        K = CLIP; N = CLIP;
        src = W2 + (size_t)s * CLIP * CLIP;
        dst = w2t + (size_t)s * CLIP * CLIP;
    }
    int tid = threadIdx.x;
    int rk = tid >> 2;           // 0..63 (k row within tile)
    int cg = (tid & 3) << 4;     // 0,16,32,48 (n col group)
    const float4* p4 = reinterpret_cast<const float4*>(src + (size_t)(k0 + rk) * N + n0 + cg);
    #pragma unroll
    for (int jj = 0; jj < 4; ++jj) {
        float4 v = p4[jj];
        T[cg + jj * 4 + 0][rk] = f2bf(v.x);
        T[cg + jj * 4 + 1][rk] = f2bf(v.y);
        T[cg + jj * 4 + 2][rk] = f2bf(v.z);
        T[cg + jj * 4 + 3][rk] = f2bf(v.w);
    }
    __syncthreads();
    // write transposed: row n = n0+rk, cols k0+cg..+15 (32B per thread)
    u16* q = dst + (size_t)(n0 + rk) * K + k0 + cg;
    const short8* tp = reinterpret_cast<const short8*>(&T[rk][cg]);
    reinterpret_cast<short8*>(q)[0] = tp[0];
    reinterpret_cast<short8*>(q)[1] = tp[1];
}

// ---- bucketing ----
__global__ void init_meta(int* meta) { if (threadIdx.x < 64) meta[threadIdx.x] = 0; }

__global__ void count_k(const int* __restrict__ sid, int* meta) {
    int i = blockIdx.x * 256 + threadIdx.x;
    if (i < BATCH) atomicAdd(&meta[sid[i]], 1);
}

__global__ void offsets_k(int* meta) {
    if (threadIdx.x == 0 && blockIdx.x == 0) {
        int off = 0, coff = 0;
        for (int s = 0; s < NSUB; ++s) {
            int c = meta[s];
            meta[26 + s] = off;          // sample offset
            meta[40 + s] = coff;         // chunk offset
            off += c; coff += (c + ROWS - 1) / ROWS;
        }
        meta[26 + NSUB] = off;
        meta[40 + NSUB] = coff;
        meta[54] = coff;                 // total chunks
    }
}

__global__ void scatter_k(const int* __restrict__ sid, int* meta, int* idxbuf) {
    int i = blockIdx.x * 256 + threadIdx.x;
    if (i < BATCH) {
        int s = sid[i];
        int p = atomicAdd(&meta[13 + s], 1);
        idxbuf[meta[26 + s] + p] = i;
    }
}

// ---- fused MLP: X[64,256] @ W1 -> relu -> @ W2 -> normalize ----
__global__ __launch_bounds__(512) void mlp_k(
    const float* __restrict__ X, const float* __restrict__ b1,
    const float* __restrict__ b2, const u16* __restrict__ w1t,
    const u16* __restrict__ w2t, const int* __restrict__ meta,
    const int* __restrict__ idxbuf, float* __restrict__ out) {

    __shared__ u16 Xs[64 * 264];       // 264 = 256+8 pad (528B stride)
    __shared__ u16 Hs[64 * 520];       // 520 = 512+8 pad (1040B stride)
    __shared__ float partial[64 * 8];
    __shared__ float scalev[64];
    __shared__ int info[4];
    __shared__ int rowidx[64];

    int tid = threadIdx.x;
    int bid = blockIdx.x;

    if (tid == 0) {
        int total = meta[54];
        if (bid < total) {
            int s = 0;
            while (s < NSUB && !(bid >= meta[40 + s] && bid < meta[40 + s + 1])) s++;
            if (s >= NSUB) { info[0] = -1; }
            else {
                int chunk = bid - meta[40 + s];
                info[0] = s;
                info[1] = meta[26 + s] + chunk * ROWS;
                info[2] = min(ROWS, meta[s] - chunk * ROWS);
            }
        } else info[0] = -1;
    }
    __syncthreads();
    if (info[0] < 0) return;
    int s = info[0], rowbase = info[1], nrows = info[2];

    if (tid < 64) rowidx[tid] = idxbuf[rowbase + min(tid, nrows - 1)];
    __syncthreads();

    // stage X tile (gather rows, fp32 -> bf16)
    {
        int row = tid >> 3, l8 = tid & 7;
        const float4* xp = reinterpret_cast<const float4*>(X + (size_t)rowidx[row] * EEG);
        u16* xd = &Xs[row * 264];
        #pragma unroll
        for (int it = 0; it < 8; ++it) {
            int c4 = l8 + it * 8;
            float4 v = xp[c4];
            union { u16 u[4]; uint2 q; } pk;
            pk.u[0] = f2bf(v.x); pk.u[1] = f2bf(v.y);
            pk.u[2] = f2bf(v.z); pk.u[3] = f2bf(v.w);
            *reinterpret_cast<uint2*>(&xd[c4 * 4]) = pk.q;
        }
    }
    __syncthreads();

    int wave = tid >> 6;
    int lane = tid & 63;
    int c = lane & 15;           // A-row / B-col / D-col
    int gl = lane >> 4;          // k-group, D-row group
    int wn0 = wave * 64;         // this wave's output column base

    // ---- layer 1: H = relu(X @ W1 + b1) ----
    f32x4 acc[4][4];
    #pragma unroll
    for (int mi = 0; mi < 4; ++mi)
        #pragma unroll
        for (int ni = 0; ni < 4; ++ni)
            acc[mi][ni] = (f32x4){0.f, 0.f, 0.f, 0.f};

    const u16* w1s = w1t + (size_t)s * CLIP * EEG;
    #pragma unroll 4
    for (int k0 = 0; k0 < EEG; k0 += 32) {
        short8 a[4], bb[4];
        #pragma unroll
        for (int mi = 0; mi < 4; ++mi)
            a[mi] = *reinterpret_cast<const short8*>(&Xs[(mi * 16 + c) * 264 + k0 + gl * 8]);
        #pragma unroll
        for (int ni = 0; ni < 4; ++ni)
            bb[ni] = *reinterpret_cast<const short8*>(&w1s[(size_t)(wn0 + ni * 16 + c) * EEG + k0 + gl * 8]);
        #pragma unroll
        for (int mi = 0; mi < 4; ++mi)
            #pragma unroll
            for (int ni = 0; ni < 4; ++ni)
                acc[mi][ni] = __builtin_amdgcn_mfma_f32_16x16x32_bf16(a[mi], bb[ni], acc[mi][ni], 0, 0, 0);
    }

    {
        float bias1[4];
        #pragma unroll
        for (int ni = 0; ni < 4; ++ni) bias1[ni] = b1[s * CLIP + wn0 + ni * 16 + c];
        #pragma unroll
        for (int mi = 0; mi < 4; ++mi)
            #pragma unroll
            for (int ni = 0; ni < 4; ++ni)
                #pragma unroll
                for (int i = 0; i < 4; ++i) {
                    float h = fmaxf(acc[mi][ni][i] + bias1[ni], 0.f);
                    Hs[(mi * 16 + gl * 4 + i) * 520 + wn0 + ni * 16 + c] = f2bf(h);
                }
    }
    __syncthreads();

    // ---- layer 2: Y = H @ W2 + b2 ----
    f32x4 acc2[4][4];
    #pragma unroll
    for (int mi = 0; mi < 4; ++mi)
        #pragma unroll
        for (int ni = 0; ni < 4; ++ni)
            acc2[mi][ni] = (f32x4){0.f, 0.f, 0.f, 0.f};

    const u16* w2s = w2t + (size_t)s * CLIP * CLIP;
    #pragma unroll 4
    for (int k0 = 0; k0 < CLIP; k0 += 32) {
        short8 a[4], bb[4];
        #pragma unroll
        for (int mi = 0; mi < 4; ++mi)
            a[mi] = *reinterpret_cast<const short8*>(&Hs[(mi * 16 + c) * 520 + k0 + gl * 8]);
        #pragma unroll
        for (int ni = 0; ni < 4; ++ni)
            bb[ni] = *reinterpret_cast<const short8*>(&w2s[(size_t)(wn0 + ni * 16 + c) * CLIP + k0 + gl * 8]);
        #pragma unroll
        for (int mi = 0; mi < 4; ++mi)
            #pragma unroll
            for (int ni = 0; ni < 4; ++ni)
                acc2[mi][ni] = __builtin_amdgcn_mfma_f32_16x16x32_bf16(a[mi], bb[ni], acc2[mi][ni], 0, 0, 0);
    }

    // bias + squared row-sums (this wave's 64 cols)
    float sq[4][4];
    {
        float bias2[4];
        #pragma unroll
        for (int ni = 0; ni < 4; ++ni) bias2[ni] = b2[s * CLIP + wn0 + ni * 16 + c];
        #pragma unroll
        for (int mi = 0; mi < 4; ++mi)
            #pragma unroll
            for (int i = 0; i < 4; ++i) sq[mi][i] = 0.f;
        #pragma unroll
        for (int mi = 0; mi < 4; ++mi)
            #pragma unroll
            for (int ni = 0; ni < 4; ++ni)
                #pragma unroll
                for (int i = 0; i < 4; ++i) {
                    float v = acc2[mi][ni][i] + bias2[ni];
                    acc2[mi][ni][i] = v;
                    sq[mi][i] += v * v;
                }
    }
    // reduce over the 16 c-lanes
    #pragma unroll
    for (int m = 1; m < 16; m <<= 1)
        #pragma unroll
        for (int mi = 0; mi < 4; ++mi)
            #pragma unroll
            for (int i = 0; i < 4; ++i)
                sq[mi][i] += __shfl_xor(sq[mi][i], m);

    if (c == 0) {
        #pragma unroll
        for (int mi = 0; mi < 4; ++mi)
            #pragma unroll
            for (int i = 0; i < 4; ++i)
                partial[(mi * 16 + gl * 4 + i) * 8 + wave] = sq[mi][i];
    }
    __syncthreads();
    if (tid < 64) {
        float t = 0.f;
        #pragma unroll
        for (int w = 0; w < 8; ++w) t += partial[tid * 8 + w];
        scalev[tid] = 1.f / fmaxf(sqrtf(t), 1e-12f);
    }
    __syncthreads();

    // scaled write-out
    #pragma unroll
    for (int mi = 0; mi < 4; ++mi)
        #pragma unroll
        for (int i = 0; i < 4; ++i) {
            int row = mi * 16 + gl * 4 + i;
            if (row < nrows) {
                float sc = scalev[row];
                float* op = out + (size_t)rowidx[row] * CLIP + wn0 + c;
                #pragma unroll
                for (int ni = 0; ni < 4; ++ni)
                    op[ni * 16] = acc2[mi][ni][i] * sc;
            }
        }
}

extern "C" void kernel_launch(void* const* d_in, const int* in_sizes, int n_in,
                              void* d_out, int out_size, void* d_ws, size_t ws_size,
                              hipStream_t stream) {
    const float* eeg = (const float*)d_in[0];
    const int* sid   = (const int*)d_in[1];
    const float* W1  = (const float*)d_in[2];
    const float* b1  = (const float*)d_in[3];
    const float* W2  = (const float*)d_in[4];
    const float* b2  = (const float*)d_in[5];
    float* out = (float*)d_out;

    u16* w1t = (u16*)d_ws;                                   // 13*512*256 bf16
    u16* w2t = w1t + (size_t)NSUB * CLIP * EEG;              // 13*512*512 bf16
    int* meta = (int*)(w2t + (size_t)NSUB * CLIP * CLIP);    // 64 ints
    int* idxbuf = meta + 64;                                 // 16384 ints

    convert_transpose<<<1248, 256, 0, stream>>>(W1, W2, w1t, w2t);
    init_meta<<<1, 64, 0, stream>>>(meta);
    count_k<<<BATCH / 256, 256, 0, stream>>>(sid, meta);
    offsets_k<<<1, 1, 0, stream>>>(meta);
    scatter_k<<<BATCH / 256, 256, 0, stream>>>(sid, meta, idxbuf);
    mlp_k<<<BATCH / ROWS + NSUB, 512, 0, stream>>>(eeg, b1, b2, w1t, w2t, meta, idxbuf, out);
}

// Round 2
// 83.315 us; speedup vs baseline: 2.3255x; 2.3255x over previous
//
#include <hip/hip_runtime.h>
#include <hip/hip_bf16.h>

// SubjectSpecificProjection: per-subject 2-layer MLP (256->512->512) + L2 normalize.
// R1: (a) counting-sort bucketing (LDS histograms, no contended global atomics);
//     (b) mlp_k at 1024 threads (16 waves, 4/SIMD) for latency hiding; XCD swizzle.

#define BATCH 16384
#define EEG 256
#define CLIP 512
#define NSUB 13
#define ROWS 64

// meta layout (ints):
#define M_BCNT 0        // [64][13]
#define M_BOFF 832      // [64][13]
#define M_SOFF 1664     // [14] sample offsets per subject
#define M_COFF 1678     // [14] chunk offsets per subject (coff[13] = total chunks)
#define M_TOT  1692     // [13] per-subject counts
#define M_IDX  1720     // [16384] sorted sample indices

typedef unsigned short u16;
typedef __attribute__((ext_vector_type(8))) short short8;
typedef __attribute__((ext_vector_type(4))) float f32x4;

__device__ __forceinline__ u16 f2bf(float f) {
    union { float f; unsigned int u; } v; v.f = f;
    unsigned int u = v.u;
    unsigned int r = (u + 0x7FFFu + ((u >> 16) & 1u)) >> 16;   // RNE
    return (u16)r;
}

// ---- weight convert + transpose: W[s][k][n] fp32 -> Wt[s][n][k] bf16 ----
__global__ __launch_bounds__(256) void convert_transpose(
    const float* __restrict__ W1, const float* __restrict__ W2,
    u16* __restrict__ w1t, u16* __restrict__ w2t) {
    __shared__ u16 T[64][72];
    int b = blockIdx.x;
    const float* src; u16* dst; int K, N;
    int s, k0, n0;
    if (b < 416) {               // W1: 13 x (256/64)x(512/64)=32 tiles
        s = b >> 5; int t = b & 31;
        k0 = (t >> 3) << 6; n0 = (t & 7) << 6;
        K = EEG; N = CLIP;
        src = W1 + (size_t)s * EEG * CLIP;
        dst = w1t + (size_t)s * CLIP * EEG;
    } else {                     // W2: 13 x 64 tiles
        b -= 416; s = b >> 6; int t = b & 63;
        k0 = (t >> 3) << 6; n0 = (t & 7) << 6;
        K = CLIP; N = CLIP;
        src = W2 + (size_t)s * CLIP * CLIP;
        dst = w2t + (size_t)s * CLIP * CLIP;
    }
    int tid = threadIdx.x;
    int rk = tid >> 2;
    int cg = (tid & 3) << 4;
    const float4* p4 = reinterpret_cast<const float4*>(src + (size_t)(k0 + rk) * N + n0 + cg);
    #pragma unroll
    for (int jj = 0; jj < 4; ++jj) {
        float4 v = p4[jj];
        T[cg + jj * 4 + 0][rk] = f2bf(v.x);
        T[cg + jj * 4 + 1][rk] = f2bf(v.y);
        T[cg + jj * 4 + 2][rk] = f2bf(v.z);
        T[cg + jj * 4 + 3][rk] = f2bf(v.w);
    }
    __syncthreads();
    u16* q = dst + (size_t)(n0 + rk) * K + k0 + cg;
    const short8* tp = reinterpret_cast<const short8*>(&T[rk][cg]);
    reinterpret_cast<short8*>(q)[0] = tp[0];
    reinterpret_cast<short8*>(q)[1] = tp[1];
}

// ---- counting-sort bucketing: hist -> scan -> scatter ----
__global__ __launch_bounds__(256) void hist_k(const int* __restrict__ sid, int* __restrict__ meta) {
    __shared__ int h[NSUB];
    int tid = threadIdx.x;
    if (tid < NSUB) h[tid] = 0;
    __syncthreads();
    int i = blockIdx.x * 256 + tid;
    atomicAdd(&h[sid[i]], 1);            // LDS atomic, ~20/address
    __syncthreads();
    if (tid < NSUB) meta[M_BCNT + blockIdx.x * NSUB + tid] = h[tid];
}

__global__ __launch_bounds__(256) void scan_k(int* __restrict__ meta) {
    __shared__ int lb[64][NSUB];
    __shared__ int tot[NSUB], so[14], co[14];
    int tid = threadIdx.x;
    for (int idx = tid; idx < 64 * NSUB; idx += 256)
        lb[idx / NSUB][idx % NSUB] = meta[M_BCNT + idx];
    __syncthreads();
    if (tid < NSUB) {                    // exclusive prefix over blocks
        int run = 0;
        for (int b = 0; b < 64; ++b) { int c = lb[b][tid]; lb[b][tid] = run; run += c; }
        tot[tid] = run;
    }
    __syncthreads();
    if (tid == 0) {
        int off = 0, c = 0;
        for (int s = 0; s < NSUB; ++s) {
            so[s] = off; co[s] = c;
            off += tot[s]; c += (tot[s] + ROWS - 1) / ROWS;
        }
        so[NSUB] = off; co[NSUB] = c;
    }
    __syncthreads();
    for (int idx = tid; idx < 64 * NSUB; idx += 256)
        meta[M_BOFF + idx] = so[idx % NSUB] + lb[idx / NSUB][idx % NSUB];
    if (tid < 14) { meta[M_SOFF + tid] = so[tid]; meta[M_COFF + tid] = co[tid]; }
    if (tid < NSUB) meta[M_TOT + tid] = tot[tid];
}

__global__ __launch_bounds__(256) void scatter2_k(const int* __restrict__ sid, int* __restrict__ meta) {
    __shared__ int h[NSUB];
    int tid = threadIdx.x;
    if (tid < NSUB) h[tid] = 0;
    __syncthreads();
    int i = blockIdx.x * 256 + tid;
    int s = sid[i];
    int r = atomicAdd(&h[s], 1);         // LDS atomic: unique local rank
    meta[M_IDX + meta[M_BOFF + blockIdx.x * NSUB + s] + r] = i;
}

// ---- fused MLP: X[64,256] @ W1 -> relu -> @ W2 -> normalize ----
__global__ __launch_bounds__(1024) void mlp_k(
    const float* __restrict__ X, const float* __restrict__ b1,
    const float* __restrict__ b2, const u16* __restrict__ w1t,
    const u16* __restrict__ w2t, const int* __restrict__ meta,
    float* __restrict__ out) {

    __shared__ u16 Xs[64 * 264];       // 33.8 KB
    __shared__ u16 Hs[64 * 520];       // 66.6 KB
    __shared__ float partial[64 * 16];
    __shared__ float scalev[64];
    __shared__ int info[4];
    __shared__ int rowidx[64];
    __shared__ int cobuf[14], sobuf[14], totbuf[NSUB];

    int tid = threadIdx.x;

    // bijective XCD swizzle (m204): contiguous chunk ranges -> same XCD L2
    int nwg = gridDim.x;
    int q = nwg >> 3, r = nwg & 7;
    int xcd = blockIdx.x & 7, idx = blockIdx.x >> 3;
    int bid = (xcd < r) ? xcd * (q + 1) + idx : r * (q + 1) + (xcd - r) * q + idx;

    if (tid < 14) { cobuf[tid] = meta[M_COFF + tid]; sobuf[tid] = meta[M_SOFF + tid]; }
    if (tid < NSUB) totbuf[tid] = meta[M_TOT + tid];
    __syncthreads();
    if (tid == 0) {
        int total = cobuf[NSUB];
        if (bid < total) {
            int s = 0;
            while (s < NSUB && !(bid >= cobuf[s] && bid < cobuf[s + 1])) s++;
            int chunk = bid - cobuf[s];
            info[0] = s;
            info[1] = sobuf[s] + chunk * ROWS;
            info[2] = min(ROWS, totbuf[s] - chunk * ROWS);
        } else info[0] = -1;
    }
    __syncthreads();
    if (info[0] < 0) return;
    int s = info[0], rowbase = info[1], nrows = info[2];

    if (tid < 64) rowidx[tid] = meta[M_IDX + rowbase + min(tid, nrows - 1)];
    __syncthreads();

    // stage X tile (gather rows, fp32 -> bf16): 1024 threads, 16 per row
    {
        int row = tid >> 4, l16 = tid & 15;
        const float4* xp = reinterpret_cast<const float4*>(X + (size_t)rowidx[row] * EEG);
        u16* xd = &Xs[row * 264];
        #pragma unroll
        for (int it = 0; it < 4; ++it) {
            int c4 = l16 + it * 16;
            float4 v = xp[c4];
            union { u16 u[4]; uint2 q; } pk;
            pk.u[0] = f2bf(v.x); pk.u[1] = f2bf(v.y);
            pk.u[2] = f2bf(v.z); pk.u[3] = f2bf(v.w);
            *reinterpret_cast<uint2*>(&xd[c4 * 4]) = pk.q;
        }
    }
    __syncthreads();

    int wave = tid >> 6;         // 0..15
    int lane = tid & 63;
    int c = lane & 15;
    int gl = lane >> 4;
    int wn0 = wave * 32;         // this wave's 32 output columns

    // ---- layer 1: H = relu(X @ W1 + b1) ----
    f32x4 acc[4][2];
    #pragma unroll
    for (int mi = 0; mi < 4; ++mi)
        #pragma unroll
        for (int ni = 0; ni < 2; ++ni)
            acc[mi][ni] = (f32x4){0.f, 0.f, 0.f, 0.f};

    const u16* w1s = w1t + (size_t)s * CLIP * EEG;
    #pragma unroll 4
    for (int k0 = 0; k0 < EEG; k0 += 32) {
        short8 a[4], bb[2];
        #pragma unroll
        for (int ni = 0; ni < 2; ++ni)
            bb[ni] = *reinterpret_cast<const short8*>(&w1s[(size_t)(wn0 + ni * 16 + c) * EEG + k0 + gl * 8]);
        #pragma unroll
        for (int mi = 0; mi < 4; ++mi)
            a[mi] = *reinterpret_cast<const short8*>(&Xs[(mi * 16 + c) * 264 + k0 + gl * 8]);
        #pragma unroll
        for (int mi = 0; mi < 4; ++mi)
            #pragma unroll
            for (int ni = 0; ni < 2; ++ni)
                acc[mi][ni] = __builtin_amdgcn_mfma_f32_16x16x32_bf16(a[mi], bb[ni], acc[mi][ni], 0, 0, 0);
    }

    {
        float bias1[2];
        #pragma unroll
        for (int ni = 0; ni < 2; ++ni) bias1[ni] = b1[s * CLIP + wn0 + ni * 16 + c];
        #pragma unroll
        for (int mi = 0; mi < 4; ++mi)
            #pragma unroll
            for (int ni = 0; ni < 2; ++ni)
                #pragma unroll
                for (int i = 0; i < 4; ++i) {
                    float h = fmaxf(acc[mi][ni][i] + bias1[ni], 0.f);
                    Hs[(mi * 16 + gl * 4 + i) * 520 + wn0 + ni * 16 + c] = f2bf(h);
                }
    }
    __syncthreads();

    // ---- layer 2: Y = H @ W2 + b2 ----
    f32x4 acc2[4][2];
    #pragma unroll
    for (int mi = 0; mi < 4; ++mi)
        #pragma unroll
        for (int ni = 0; ni < 2; ++ni)
            acc2[mi][ni] = (f32x4){0.f, 0.f, 0.f, 0.f};

    const u16* w2s = w2t + (size_t)s * CLIP * CLIP;
    #pragma unroll 4
    for (int k0 = 0; k0 < CLIP; k0 += 32) {
        short8 a[4], bb[2];
        #pragma unroll
        for (int ni = 0; ni < 2; ++ni)
            bb[ni] = *reinterpret_cast<const short8*>(&w2s[(size_t)(wn0 + ni * 16 + c) * CLIP + k0 + gl * 8]);
        #pragma unroll
        for (int mi = 0; mi < 4; ++mi)
            a[mi] = *reinterpret_cast<const short8*>(&Hs[(mi * 16 + c) * 520 + k0 + gl * 8]);
        #pragma unroll
        for (int mi = 0; mi < 4; ++mi)
            #pragma unroll
            for (int ni = 0; ni < 2; ++ni)
                acc2[mi][ni] = __builtin_amdgcn_mfma_f32_16x16x32_bf16(a[mi], bb[ni], acc2[mi][ni], 0, 0, 0);
    }

    // bias + squared row-sums (this wave's 32 cols)
    float sq[4][4];
    {
        float bias2[2];
        #pragma unroll
        for (int ni = 0; ni < 2; ++ni) bias2[ni] = b2[s * CLIP + wn0 + ni * 16 + c];
        #pragma unroll
        for (int mi = 0; mi < 4; ++mi)
            #pragma unroll
            for (int i = 0; i < 4; ++i) sq[mi][i] = 0.f;
        #pragma unroll
        for (int mi = 0; mi < 4; ++mi)
            #pragma unroll
            for (int ni = 0; ni < 2; ++ni)
                #pragma unroll
                for (int i = 0; i < 4; ++i) {
                    float v = acc2[mi][ni][i] + bias2[ni];
                    acc2[mi][ni][i] = v;
                    sq[mi][i] += v * v;
                }
    }
    #pragma unroll
    for (int m = 1; m < 16; m <<= 1)
        #pragma unroll
        for (int mi = 0; mi < 4; ++mi)
            #pragma unroll
            for (int i = 0; i < 4; ++i)
                sq[mi][i] += __shfl_xor(sq[mi][i], m);

    if (c == 0) {
        #pragma unroll
        for (int mi = 0; mi < 4; ++mi)
            #pragma unroll
            for (int i = 0; i < 4; ++i)
                partial[(mi * 16 + gl * 4 + i) * 16 + wave] = sq[mi][i];
    }
    __syncthreads();
    if (tid < 64) {
        float t = 0.f;
        #pragma unroll
        for (int w = 0; w < 16; ++w) t += partial[tid * 16 + w];
        scalev[tid] = 1.f / fmaxf(sqrtf(t), 1e-12f);
    }
    __syncthreads();

    #pragma unroll
    for (int mi = 0; mi < 4; ++mi)
        #pragma unroll
        for (int i = 0; i < 4; ++i) {
            int row = mi * 16 + gl * 4 + i;
            if (row < nrows) {
                float sc = scalev[row];
                float* op = out + (size_t)rowidx[row] * CLIP + wn0 + c;
                #pragma unroll
                for (int ni = 0; ni < 2; ++ni)
                    op[ni * 16] = acc2[mi][ni][i] * sc;
            }
        }
}

extern "C" void kernel_launch(void* const* d_in, const int* in_sizes, int n_in,
                              void* d_out, int out_size, void* d_ws, size_t ws_size,
                              hipStream_t stream) {
    const float* eeg = (const float*)d_in[0];
    const int* sid   = (const int*)d_in[1];
    const float* W1  = (const float*)d_in[2];
    const float* b1  = (const float*)d_in[3];
    const float* W2  = (const float*)d_in[4];
    const float* b2  = (const float*)d_in[5];
    float* out = (float*)d_out;

    u16* w1t = (u16*)d_ws;                                   // 13*512*256 bf16
    u16* w2t = w1t + (size_t)NSUB * CLIP * EEG;              // 13*512*512 bf16
    int* meta = (int*)(w2t + (size_t)NSUB * CLIP * CLIP);    // ~1720 + 16384 ints

    convert_transpose<<<1248, 256, 0, stream>>>(W1, W2, w1t, w2t);
    hist_k<<<BATCH / 256, 256, 0, stream>>>(sid, meta);
    scan_k<<<1, 256, 0, stream>>>(meta);
    scatter2_k<<<BATCH / 256, 256, 0, stream>>>(sid, meta);
    mlp_k<<<BATCH / ROWS + NSUB, 1024, 0, stream>>>(eeg, b1, b2, w1t, w2t, meta, out);
}